// Round 3
// baseline (1677.083 us; speedup 1.0000x reference)
//
#include <hip/hip_runtime.h>

// Batched Kalman filter: one thread per batch element, sequential over T.
// Latency fix vs R0: software pipeline of depth 8 with fully-unrolled slot
// registers (SSA renaming, no rotation movs) — each global load is issued
// DEPTH steps before first use (~7*250 cyc of cover vs ~900 cyc HBM latency).

#define DEPTH 8

__global__ __launch_bounds__(64, 1)
void kalman_seq(const float* __restrict__ zl,
                const float* __restrict__ mu0,
                float* __restrict__ out,
                int N, int T)
{
    const int n = blockIdx.x * 64 + threadIdx.x;
    if (n >= N) return;

    const float a  = 0.999f;   // 1 - (B/M)*DT
    const float cA = -0.01f;   // -(K/M)*DT
    const float dA = 0.01f;    // DT

    float4 m4 = reinterpret_cast<const float4*>(mu0)[n];
    float m0 = m4.x, m1 = m4.y, m2 = m4.z, m3 = m4.w;

    // Sig = I (upper triangle)
    float P00=1.f, P01=0.f, P02=0.f, P03=0.f;
    float P11=1.f, P12=0.f, P13=0.f;
    float P22=1.f, P23=0.f, P33=1.f;

    const long strideZ = (long)N * 5;
    const long strideY = (long)N * 2;
    const float* zp = zl + (long)n * 5;
    float* outp = out + (long)n * 2;

    // pipeline slot registers — always indexed with compile-time constants
    float bz0[DEPTH], bz1[DEPTH], bL0[DEPTH], bL1[DEPTH], bL2[DEPTH];

    #pragma unroll
    for (int u = 0; u < DEPTH; ++u) {
        const float* p = zp + (long)u * strideZ;   // T=2048 >= DEPTH, no guard needed
        bz0[u] = p[0]; bz1[u] = p[1]; bL0[u] = p[2]; bL1[u] = p[3]; bL2[u] = p[4];
    }

    for (int tb = 0; tb < T; tb += DEPTH) {
        #pragma unroll
        for (int u = 0; u < DEPTH; ++u) {
            const int t = tb + u;

            // consume slot u (load issued DEPTH steps ago — long since landed)
            const float z0 = bz0[u], z1 = bz1[u];
            const float L0 = bL0[u], L1 = bL1[u], L2 = bL2[u];

            // refill slot u for step t+DEPTH (no deps on this body's compute)
            if (t + DEPTH < T) {
                const float* p = zp + (long)(t + DEPTH) * strideZ;
                bz0[u] = p[0]; bz1[u] = p[1];
                bL0[u] = p[2]; bL1[u] = p[3]; bL2[u] = p[4];
            }

            // ---- predict mean: mp = A mu ----
            float mp0 = a * m0 + cA * m2;
            float mp1 = a * m1 + cA * m3;
            float mp2 = dA * m0 + m2;
            float mp3 = dA * m1 + m3;

            // ---- M = A P (P symmetric) ----
            float M00 = a * P00 + cA * P02;
            float M01 = a * P01 + cA * P12;
            float M02 = a * P02 + cA * P22;
            float M03 = a * P03 + cA * P23;
            float M10 = a * P01 + cA * P03;
            float M11 = a * P11 + cA * P13;
            float M12 = a * P12 + cA * P23;
            float M13 = a * P13 + cA * P33;
            float M20 = dA * P00 + P02;
            float M21 = dA * P01 + P12;
            float M22 = dA * P02 + P22;
            float M23 = dA * P03 + P23;
            float M30 = dA * P01 + P03;
            float M31 = dA * P11 + P13;
            float M33 = dA * P13 + P33;

            // ---- Q = M A^T + diag(1,1,0,0), upper triangle ----
            float Q00 = a * M00 + cA * M02 + 1.0f;
            float Q01 = a * M01 + cA * M03;
            float Q02 = dA * M00 + M02;
            float Q03 = dA * M01 + M03;
            float Q11 = a * M11 + cA * M13 + 1.0f;
            float Q12 = dA * M10 + M12;
            float Q13 = dA * M11 + M13;
            float Q22 = dA * M20 + M22;
            float Q23 = dA * M21 + M23;
            float Q33 = dA * M31 + M33;

            // ---- measurement noise R from Cholesky factors ----
            float l00 = __expf(L0);
            float l10 = L1;
            float l11 = __expf(L2);
            float R00 = l00 * l00;
            float R01 = l00 * l10;
            float R11 = l10 * l10 + l11 * l11;

            // ---- innovation covariance S (2x2 sym) and inverse ----
            float S00 = Q22 + R00;
            float S01 = Q23 + R01;
            float S11 = Q33 + R11;
            float det = S00 * S11 - S01 * S01;
            float inv = __builtin_amdgcn_rcpf(det);
            float iS00 = S11 * inv;
            float iS01 = -S01 * inv;
            float iS11 = S00 * inv;

            // ---- Kalman gain K = Q[:,2:4] @ Sinv ----
            float K00 = Q02 * iS00 + Q03 * iS01;
            float K01 = Q02 * iS01 + Q03 * iS11;
            float K10 = Q12 * iS00 + Q13 * iS01;
            float K11 = Q12 * iS01 + Q13 * iS11;
            float K20 = Q22 * iS00 + Q23 * iS01;
            float K21 = Q22 * iS01 + Q23 * iS11;
            float K30 = Q23 * iS00 + Q33 * iS01;
            float K31 = Q23 * iS01 + Q33 * iS11;

            // ---- mean update ----
            float in0 = z0 - mp2;
            float in1 = z1 - mp3;
            m0 = mp0 + K00 * in0 + K01 * in1;
            m1 = mp1 + K10 * in0 + K11 * in1;
            m2 = mp2 + K20 * in0 + K21 * in1;
            m3 = mp3 + K30 * in0 + K31 * in1;

            // ---- covariance update: P = Q - K * Q[2:4,:] ----
            P00 = Q00 - K00 * Q02 - K01 * Q03;
            P01 = Q01 - K00 * Q12 - K01 * Q13;
            P02 = Q02 - K00 * Q22 - K01 * Q23;
            P03 = Q03 - K00 * Q23 - K01 * Q33;
            P11 = Q11 - K10 * Q12 - K11 * Q13;
            P12 = Q12 - K10 * Q22 - K11 * Q23;
            P13 = Q13 - K10 * Q23 - K11 * Q33;
            P22 = Q22 - K20 * Q22 - K21 * Q23;
            P23 = Q23 - K20 * Q23 - K21 * Q33;
            P33 = Q33 - K30 * Q23 - K31 * Q33;

            // ---- emit y = mu[2:4] ----
            reinterpret_cast<float2*>(outp + (long)t * strideY)[0] = make_float2(m2, m3);
        }
    }
}

extern "C" void kernel_launch(void* const* d_in, const int* in_sizes, int n_in,
                              void* d_out, int out_size, void* d_ws, size_t ws_size,
                              hipStream_t stream) {
    const float* zl  = (const float*)d_in[0];
    const float* mu0 = (const float*)d_in[1];
    float* out = (float*)d_out;

    int N = in_sizes[1] / 4;             // 4096
    int T = in_sizes[0] / (N * 5);       // 2048

    int block = 64;
    int grid = (N + block - 1) / block;  // 64 blocks -> 64 CUs, 1 wave each
    kalman_seq<<<grid, block, 0, stream>>>(zl, mu0, out, N, T);
}

// Round 4
// 725.978 us; speedup vs baseline: 2.3101x; 2.3101x over previous
//
#include <hip/hip_runtime.h>

// Batched Kalman filter, one thread per element, T sequential.
// R3 lesson: register-dest loads get compiler-placed waitcnts -> full HBM
// latency exposed per step. Fix: stage z/Lh via global_load_lds (no dest reg,
// no compiler wait), double-buffered LDS tiles of TS=8 steps, ONE explicit
// counted s_waitcnt vmcnt(40) per tile.

#define TS 8

__global__ __launch_bounds__(64, 1)
void kalman_lds(const float* __restrict__ zl,
                const float* __restrict__ mu0,
                float* __restrict__ out,
                int N, int T)
{
    // SoA planes: lds[buf][j][step][lane], stride-4B across lanes (conflict-free)
    __shared__ float lds[2][5][TS][64];

    const int lane = threadIdx.x;
    const int n    = blockIdx.x * 64 + lane;   // N = 4096 = 64 blocks * 64 lanes exact

    const float a  = 0.999f;   // 1 - (B/M)*DT
    const float cA = -0.01f;   // -(K/M)*DT
    const float dA = 0.01f;    // DT

    float4 m4 = reinterpret_cast<const float4*>(mu0)[n];
    float m0 = m4.x, m1 = m4.y, m2 = m4.z, m3 = m4.w;

    float P00=1.f, P01=0.f, P02=0.f, P03=0.f;
    float P11=1.f, P12=0.f, P13=0.f;
    float P22=1.f, P23=0.f, P33=1.f;

    const long step5N   = (long)N * 5;          // floats per time step
    const long strideY  = (long)N * 2;
    const float* zlane  = zl + (long)n * 5;     // this lane's column at t=0
    float* outp         = out + (long)n * 2;

    // ---- issue tile 0 into buf 0 (40 loads, no reg dests) ----
    #pragma unroll
    for (int s = 0; s < TS; ++s) {
        const float* g = zlane + (long)s * step5N;
        #pragma unroll
        for (int j = 0; j < 5; ++j) {
            __builtin_amdgcn_global_load_lds(
                (const __attribute__((address_space(1))) unsigned int*)(g + j),
                (__attribute__((address_space(3))) unsigned int*)&lds[0][j][s][0],
                4, 0, 0);
        }
    }

    const int NT = T / TS;   // 256 tiles
    for (int tile = 0; tile < NT; ++tile) {
        const int b = tile & 1;

        // ---- prefetch next tile into buf b^1 (reload tile 0 on last iter to
        //      keep the outstanding-op count uniform) ----
        {
            const int nt = (tile + 1 < NT) ? (tile + 1) : 0;
            const float* gb = zlane + (long)nt * TS * step5N;
            #pragma unroll
            for (int s = 0; s < TS; ++s) {
                const float* g = gb + (long)s * step5N;
                #pragma unroll
                for (int j = 0; j < 5; ++j) {
                    __builtin_amdgcn_global_load_lds(
                        (const __attribute__((address_space(1))) unsigned int*)(g + j),
                        (__attribute__((address_space(3))) unsigned int*)&lds[b ^ 1][j][s][0],
                        4, 0, 0);
                }
            }
        }

        // ---- current tile resident when all but the newest 40 VMEM ops done:
        // issue order ... [tile loads x40][y stores x8][next-tile loads x40] ----
        asm volatile("s_waitcnt vmcnt(40)" ::: "memory");

        // LDS -> reg, 1-ahead pipeline (covers ~120cyc ds_read latency)
        float c0 = lds[b][0][0][lane], c1 = lds[b][1][0][lane],
              cl0 = lds[b][2][0][lane], cl1 = lds[b][3][0][lane], cl2 = lds[b][4][0][lane];

        #pragma unroll
        for (int s = 0; s < TS; ++s) {
            float x0, x1, y0, y1, y2;
            if (s + 1 < TS) {
                x0 = lds[b][0][s+1][lane]; x1 = lds[b][1][s+1][lane];
                y0 = lds[b][2][s+1][lane]; y1 = lds[b][3][s+1][lane]; y2 = lds[b][4][s+1][lane];
            } else { x0 = x1 = y0 = y1 = y2 = 0.f; }

            const float z0 = c0, z1 = c1, L0 = cl0, L1 = cl1, L2 = cl2;

            // ---- predict mean: mp = A mu ----
            float mp0 = a * m0 + cA * m2;
            float mp1 = a * m1 + cA * m3;
            float mp2 = dA * m0 + m2;
            float mp3 = dA * m1 + m3;

            // ---- M = A P (P symmetric) ----
            float M00 = a * P00 + cA * P02;
            float M01 = a * P01 + cA * P12;
            float M02 = a * P02 + cA * P22;
            float M03 = a * P03 + cA * P23;
            float M10 = a * P01 + cA * P03;
            float M11 = a * P11 + cA * P13;
            float M12 = a * P12 + cA * P23;
            float M13 = a * P13 + cA * P33;
            float M20 = dA * P00 + P02;
            float M21 = dA * P01 + P12;
            float M22 = dA * P02 + P22;
            float M23 = dA * P03 + P23;
            float M30 = dA * P01 + P03;
            float M31 = dA * P11 + P13;
            float M33 = dA * P13 + P33;

            // ---- Q = M A^T + diag(1,1,0,0), upper triangle ----
            float Q00 = a * M00 + cA * M02 + 1.0f;
            float Q01 = a * M01 + cA * M03;
            float Q02 = dA * M00 + M02;
            float Q03 = dA * M01 + M03;
            float Q11 = a * M11 + cA * M13 + 1.0f;
            float Q12 = dA * M10 + M12;
            float Q13 = dA * M11 + M13;
            float Q22 = dA * M20 + M22;
            float Q23 = dA * M21 + M23;
            float Q33 = dA * M31 + M33;

            // ---- measurement noise R from Cholesky factors ----
            float l00 = __expf(L0);
            float l10 = L1;
            float l11 = __expf(L2);
            float R00 = l00 * l00;
            float R01 = l00 * l10;
            float R11 = l10 * l10 + l11 * l11;

            // ---- innovation covariance S (2x2 sym) and inverse ----
            float S00 = Q22 + R00;
            float S01 = Q23 + R01;
            float S11 = Q33 + R11;
            float det = S00 * S11 - S01 * S01;
            float inv = __builtin_amdgcn_rcpf(det);
            float iS00 = S11 * inv;
            float iS01 = -S01 * inv;
            float iS11 = S00 * inv;

            // ---- Kalman gain K = Q[:,2:4] @ Sinv ----
            float K00 = Q02 * iS00 + Q03 * iS01;
            float K01 = Q02 * iS01 + Q03 * iS11;
            float K10 = Q12 * iS00 + Q13 * iS01;
            float K11 = Q12 * iS01 + Q13 * iS11;
            float K20 = Q22 * iS00 + Q23 * iS01;
            float K21 = Q22 * iS01 + Q23 * iS11;
            float K30 = Q23 * iS00 + Q33 * iS01;
            float K31 = Q23 * iS01 + Q33 * iS11;

            // ---- mean update ----
            float in0 = z0 - mp2;
            float in1 = z1 - mp3;
            m0 = mp0 + K00 * in0 + K01 * in1;
            m1 = mp1 + K10 * in0 + K11 * in1;
            m2 = mp2 + K20 * in0 + K21 * in1;
            m3 = mp3 + K30 * in0 + K31 * in1;

            // ---- covariance update: P = Q - K * Q[2:4,:] ----
            P00 = Q00 - K00 * Q02 - K01 * Q03;
            P01 = Q01 - K00 * Q12 - K01 * Q13;
            P02 = Q02 - K00 * Q22 - K01 * Q23;
            P03 = Q03 - K00 * Q23 - K01 * Q33;
            P11 = Q11 - K10 * Q12 - K11 * Q13;
            P12 = Q12 - K10 * Q22 - K11 * Q23;
            P13 = Q13 - K10 * Q23 - K11 * Q33;
            P22 = Q22 - K20 * Q22 - K21 * Q23;
            P23 = Q23 - K20 * Q23 - K21 * Q33;
            P33 = Q33 - K30 * Q23 - K31 * Q33;

            // ---- emit y = mu[2:4] ----
            const int t = tile * TS + s;
            reinterpret_cast<float2*>(outp + (long)t * strideY)[0] = make_float2(m2, m3);

            c0 = x0; c1 = x1; cl0 = y0; cl1 = y1; cl2 = y2;
        }
    }
}

extern "C" void kernel_launch(void* const* d_in, const int* in_sizes, int n_in,
                              void* d_out, int out_size, void* d_ws, size_t ws_size,
                              hipStream_t stream) {
    const float* zl  = (const float*)d_in[0];
    const float* mu0 = (const float*)d_in[1];
    float* out = (float*)d_out;

    int N = in_sizes[1] / 4;             // 4096
    int T = in_sizes[0] / (N * 5);       // 2048

    int block = 64;
    int grid = N / block;                // 64 blocks, 1 wave each
    kalman_lds<<<grid, block, 0, stream>>>(zl, mu0, out, N, T);
}

// Round 6
// 704.319 us; speedup vs baseline: 2.3811x; 1.0308x over previous
//
#include <hip/hip_runtime.h>

// Batched Kalman filter, one thread per element, T sequential.
// R4 lesson: global_load_lds + counted vmcnt gave 2.7x. Remaining stall:
//  (a) per-step rotated ds_reads expose LDS latency -> batch all 40 reads
//      into regs at tile start (compile-time indices, compiler overlaps);
//  (b) vmcnt(40) waited on y-stores -> vmcnt(8) excludes exactly the 8
//      stores issued after the current tile's loads.
// Issue order per iter k: [wait vmcnt(8): drains tile-k loads]
//   [40 ds_read -> r regs] [prefetch tile k+1: 40 global_load_lds]
//   [8 steps compute, 8 scattered y stores].
// Max outstanding VMEM/wave = 48 <= 63 (vmcnt capacity).

#define TS 8

__global__ __launch_bounds__(64, 1)
void kalman_lds(const float* __restrict__ zl,
                const float* __restrict__ mu0,
                float* __restrict__ out,
                int N, int T)
{
    // SoA planes: lds[buf][j][step][lane]; across lanes stride 4B -> 2 lanes/bank, free
    __shared__ float lds[2][5][TS][64];

    const int lane = threadIdx.x;
    const int n    = blockIdx.x * 64 + lane;   // N = 4096 = 64 blocks * 64 lanes

    const float a  = 0.999f;   // 1 - (B/M)*DT
    const float cA = -0.01f;   // -(K/M)*DT
    const float dA = 0.01f;    // DT

    float4 m4 = reinterpret_cast<const float4*>(mu0)[n];
    float m0 = m4.x, m1 = m4.y, m2 = m4.z, m3 = m4.w;

    float P00=1.f, P01=0.f, P02=0.f, P03=0.f;
    float P11=1.f, P12=0.f, P13=0.f;
    float P22=1.f, P23=0.f, P33=1.f;

    const long step5N  = (long)N * 5;
    const long strideY = (long)N * 2;
    const float* zlane = zl + (long)n * 5;
    float* outp        = out + (long)n * 2;

    // ---- prologue: issue tile 0 into buf 0, drain fully once ----
    #pragma unroll
    for (int s = 0; s < TS; ++s) {
        const float* g = zlane + (long)s * step5N;
        #pragma unroll
        for (int j = 0; j < 5; ++j) {
            __builtin_amdgcn_global_load_lds(
                (const __attribute__((address_space(1))) unsigned int*)(g + j),
                (__attribute__((address_space(3))) unsigned int*)&lds[0][j][s][0],
                4, 0, 0);
        }
    }
    asm volatile("s_waitcnt vmcnt(0)" ::: "memory");

    const int NT = T / TS;   // 256 tiles
    for (int tile = 0; tile < NT; ++tile) {
        const int b = tile & 1;

        // drain current tile's loads; keep the 8 newest VMEM ops (y stores) in flight
        asm volatile("s_waitcnt vmcnt(8)" ::: "memory");

        // ---- batched LDS -> reg: all TS*5 values, compile-time indexed ----
        float r[TS * 5];
        #pragma unroll
        for (int s = 0; s < TS; ++s) {
            #pragma unroll
            for (int j = 0; j < 5; ++j)
                r[s * 5 + j] = lds[b][j][s][lane];
        }

        // ---- prefetch next tile into buf b^1 (reload tile 0 on last iter
        //      to keep the outstanding-op count uniform) ----
        {
            const int nt = (tile + 1 < NT) ? (tile + 1) : 0;
            const float* gb = zlane + (long)nt * TS * step5N;
            #pragma unroll
            for (int s = 0; s < TS; ++s) {
                const float* g = gb + (long)s * step5N;
                #pragma unroll
                for (int j = 0; j < 5; ++j) {
                    __builtin_amdgcn_global_load_lds(
                        (const __attribute__((address_space(1))) unsigned int*)(g + j),
                        (__attribute__((address_space(3))) unsigned int*)&lds[b ^ 1][j][s][0],
                        4, 0, 0);
                }
            }
        }

        float* yp = outp + (long)(tile * TS) * strideY;

        #pragma unroll
        for (int s = 0; s < TS; ++s) {
            const float z0 = r[s*5+0], z1 = r[s*5+1];
            const float L0 = r[s*5+2], L1 = r[s*5+3], L2 = r[s*5+4];

            // ---- predict mean: mp = A mu ----
            float mp0 = a * m0 + cA * m2;
            float mp1 = a * m1 + cA * m3;
            float mp2 = dA * m0 + m2;
            float mp3 = dA * m1 + m3;

            // ---- M = A P (P symmetric) ----
            float M00 = a * P00 + cA * P02;
            float M01 = a * P01 + cA * P12;
            float M02 = a * P02 + cA * P22;
            float M03 = a * P03 + cA * P23;
            float M10 = a * P01 + cA * P03;
            float M11 = a * P11 + cA * P13;
            float M12 = a * P12 + cA * P23;
            float M13 = a * P13 + cA * P33;
            float M20 = dA * P00 + P02;
            float M21 = dA * P01 + P12;
            float M22 = dA * P02 + P22;
            float M23 = dA * P03 + P23;
            float M30 = dA * P01 + P03;
            float M31 = dA * P11 + P13;
            float M33 = dA * P13 + P33;

            // ---- Q = M A^T + diag(1,1,0,0), upper triangle ----
            float Q00 = a * M00 + cA * M02 + 1.0f;
            float Q01 = a * M01 + cA * M03;
            float Q02 = dA * M00 + M02;
            float Q03 = dA * M01 + M03;
            float Q11 = a * M11 + cA * M13 + 1.0f;
            float Q12 = dA * M10 + M12;
            float Q13 = dA * M11 + M13;
            float Q22 = dA * M20 + M22;
            float Q23 = dA * M21 + M23;
            float Q33 = dA * M31 + M33;

            // ---- measurement noise R from Cholesky factors ----
            float l00 = __expf(L0);
            float l10 = L1;
            float l11 = __expf(L2);
            float R00 = l00 * l00;
            float R01 = l00 * l10;
            float R11 = l10 * l10 + l11 * l11;

            // ---- innovation covariance S (2x2 sym) and inverse ----
            float S00 = Q22 + R00;
            float S01 = Q23 + R01;
            float S11 = Q33 + R11;
            float det = S00 * S11 - S01 * S01;
            float inv = __builtin_amdgcn_rcpf(det);
            float iS00 = S11 * inv;
            float iS01 = -S01 * inv;
            float iS11 = S00 * inv;

            // ---- Kalman gain K = Q[:,2:4] @ Sinv ----
            float K00 = Q02 * iS00 + Q03 * iS01;
            float K01 = Q02 * iS01 + Q03 * iS11;
            float K10 = Q12 * iS00 + Q13 * iS01;
            float K11 = Q12 * iS01 + Q13 * iS11;
            float K20 = Q22 * iS00 + Q23 * iS01;
            float K21 = Q22 * iS01 + Q23 * iS11;
            float K30 = Q23 * iS00 + Q33 * iS01;
            float K31 = Q23 * iS01 + Q33 * iS11;

            // ---- mean update ----
            float in0 = z0 - mp2;
            float in1 = z1 - mp3;
            m0 = mp0 + K00 * in0 + K01 * in1;
            m1 = mp1 + K10 * in0 + K11 * in1;
            m2 = mp2 + K20 * in0 + K21 * in1;
            m3 = mp3 + K30 * in0 + K31 * in1;

            // ---- covariance update: P = Q - K * Q[2:4,:] ----
            P00 = Q00 - K00 * Q02 - K01 * Q03;
            P01 = Q01 - K00 * Q12 - K01 * Q13;
            P02 = Q02 - K00 * Q22 - K01 * Q23;
            P03 = Q03 - K00 * Q23 - K01 * Q33;
            P11 = Q11 - K10 * Q12 - K11 * Q13;
            P12 = Q12 - K10 * Q22 - K11 * Q23;
            P13 = Q13 - K10 * Q23 - K11 * Q33;
            P22 = Q22 - K20 * Q22 - K21 * Q23;
            P23 = Q23 - K20 * Q23 - K21 * Q33;
            P33 = Q33 - K30 * Q23 - K31 * Q33;

            // ---- emit y = mu[2:4] ----
            reinterpret_cast<float2*>(yp)[0] = make_float2(m2, m3);
            yp += strideY;
        }
    }
}

extern "C" void kernel_launch(void* const* d_in, const int* in_sizes, int n_in,
                              void* d_out, int out_size, void* d_ws, size_t ws_size,
                              hipStream_t stream) {
    const float* zl  = (const float*)d_in[0];
    const float* mu0 = (const float*)d_in[1];
    float* out = (float*)d_out;

    int N = in_sizes[1] / 4;             // 4096
    int T = in_sizes[0] / (N * 5);       // 2048

    int block = 64;
    int grid = N / block;                // 64 blocks, 1 wave each
    kalman_lds<<<grid, block, 0, stream>>>(zl, mu0, out, N, T);
}